// Round 1
// baseline (448.612 us; speedup 1.0000x reference)
//
#include <hip/hip_runtime.h>

// ConvSelfAttentionModule: B=4, C=256, CQK=128, N=4096 (64x64), fp32 in/out.
// Two-phase fused attention (softmax axis is NOT the contracted axis, so
// online-softmax can't fuse into output):
//   k_wsplit  : split fp32 weights -> f16 hi/lo pair (for fp32-accurate MFMA proj)
//   k_xsplit  : transpose+split x[b][c][n] -> xT hi/lo [b][n][c] f16
//   k_proj    : split-f16 MFMA GEMM -> qk[b][i][0:128]=q, [128:256]=k ; vv[b][c][i]
//   k_stats   : phase A — per-row max & sumexp of S = q·k^T (streaming, online)
//   k_scalev  : vv *= 1/rowsum  (fold softmax denominator into V)
//   k_attn_av : phase B — recompute S tiles, P=exp(s-m) -> LDS, AV MFMA, +x residual
// Error budget: q,k stored f16 => delta_s ~ 5e-3 std => out err ~0.02 << 0.1 thr.

typedef _Float16 f16;
typedef _Float16 f16x4v __attribute__((ext_vector_type(4)));
typedef _Float16 f16x8v __attribute__((ext_vector_type(8)));
typedef float f32x4v __attribute__((ext_vector_type(4)));

static __device__ __forceinline__ f32x4v mfma16(f16x8v a, f16x8v b, f32x4v c) {
  // D[m][n] = sum_k A[m][k]*B[k][n]; a-frag: m=lane&15, k=quad*8+j;
  // b-frag from B^T rows: n=lane&15, k=quad*8+j; D: col(n)=lane&15, row(m)=quad*4+reg
  return __builtin_amdgcn_mfma_f32_16x16x32_f16(a, b, c, 0, 0, 0);
}

// ---------------- kernel 0a: weight split ----------------
__global__ void k_wsplit(const float* __restrict__ wq, const float* __restrict__ bq,
                         const float* __restrict__ wk, const float* __restrict__ bk,
                         const float* __restrict__ wv, const float* __restrict__ bv,
                         f16* __restrict__ wh, f16* __restrict__ wl, float* __restrict__ bcat) {
  int o = blockIdx.x;          // 512 output rows: 0-127 q, 128-255 k, 256-511 v
  int c = threadIdx.x;         // 256
  const float* wrow; float bias;
  if (o < 128)      { wrow = wq + (size_t)o * 256;        bias = bq[o]; }
  else if (o < 256) { wrow = wk + (size_t)(o - 128) * 256; bias = bk[o - 128]; }
  else              { wrow = wv + (size_t)(o - 256) * 256; bias = bv[o - 256]; }
  float v = wrow[c];
  f16 h = (f16)v;
  wh[(size_t)o * 256 + c] = h;
  wl[(size_t)o * 256 + c] = (f16)(v - (float)h);
  if (c == 0) bcat[o] = bias;
}

// ---------------- kernel 0b: x transpose + split ----------------
// x[b][c][n] f32 -> xh/xl [b][n][c] f16
__global__ void k_xsplit(const float* __restrict__ x, f16* __restrict__ xh, f16* __restrict__ xl) {
  __shared__ float t[64][65];
  int b = blockIdx.z, c0 = blockIdx.y * 64, n0 = blockIdx.x * 64;
  int tx = threadIdx.x & 63, ty = threadIdx.x >> 6;
  const float* xb = x + ((size_t)b * 256 + c0) * 4096 + n0;
#pragma unroll
  for (int r = ty; r < 64; r += 4) t[r][tx] = xb[(size_t)r * 4096 + tx];
  __syncthreads();
  f16* dh = xh + ((size_t)b * 4096 + n0) * 256 + c0;
  f16* dl = xl + ((size_t)b * 4096 + n0) * 256 + c0;
#pragma unroll
  for (int r = ty; r < 64; r += 4) {
    float v = t[tx][r];                      // (c=c0+tx, n=n0+r)
    f16 h = (f16)v;
    dh[(size_t)r * 256 + tx] = h;
    dl[(size_t)r * 256 + tx] = (f16)(v - (float)h);
  }
}

// ---------------- kernel 1: projections (split-f16 NT GEMM) ----------------
// D[i][o] = sum_c xT[i][c]*W[o][c] + b[o];  o<256 -> qk[b][i][o] ; else vv[b][o-256][i]
__global__ void __launch_bounds__(256, 2)
k_proj(const f16* __restrict__ xh, const f16* __restrict__ xl,
       const f16* __restrict__ wh, const f16* __restrict__ wl,
       const float* __restrict__ bcat, f16* __restrict__ qk, f16* __restrict__ vv) {
  constexpr int LDK = 40;  // 32 + 8 pad (2-way bank alias only; rows stay 16B-aligned)
  __shared__ f16 sAh[64 * LDK], sAl[64 * LDK], sWh[64 * LDK], sWl[64 * LDK];
  int b = blockIdx.z, m0 = blockIdx.y * 64, n0 = blockIdx.x * 64;
  int tid = threadIdx.x, lane = tid & 63, w = tid >> 6;
  int col = lane & 15, quad = lane >> 4, ko = quad * 8;
  const f16* Ah = xh + ((size_t)b * 4096 + m0) * 256;
  const f16* Al = xl + ((size_t)b * 4096 + m0) * 256;
  const f16* Wh = wh + (size_t)n0 * 256;
  const f16* Wl = wl + (size_t)n0 * 256;
  f32x4v acc[4] = {};
  for (int k0 = 0; k0 < 256; k0 += 32) {
    __syncthreads();
    {
      int r = tid >> 3, kk = (tid & 7) * 4;
#pragma unroll
      for (int rr = r; rr < 64; rr += 32) {
        *(f16x4v*)&sAh[rr * LDK + kk] = *(const f16x4v*)&Ah[(size_t)rr * 256 + k0 + kk];
        *(f16x4v*)&sAl[rr * LDK + kk] = *(const f16x4v*)&Al[(size_t)rr * 256 + k0 + kk];
        *(f16x4v*)&sWh[rr * LDK + kk] = *(const f16x4v*)&Wh[(size_t)rr * 256 + k0 + kk];
        *(f16x4v*)&sWl[rr * LDK + kk] = *(const f16x4v*)&Wl[(size_t)rr * 256 + k0 + kk];
      }
    }
    __syncthreads();
    int mrow = w * 16 + col;
    f16x8v ah = *(const f16x8v*)&sAh[mrow * LDK + ko];
    f16x8v al = *(const f16x8v*)&sAl[mrow * LDK + ko];
#pragma unroll
    for (int ns = 0; ns < 4; ns++) {
      int nrow = ns * 16 + col;
      f16x8v bh = *(const f16x8v*)&sWh[nrow * LDK + ko];
      f16x8v bl = *(const f16x8v*)&sWl[nrow * LDK + ko];
      acc[ns] = mfma16(al, bh, acc[ns]);   // small terms first
      acc[ns] = mfma16(ah, bl, acc[ns]);
      acc[ns] = mfma16(ah, bh, acc[ns]);
    }
  }
  bool isqk = (n0 < 256);  // block-uniform
#pragma unroll
  for (int ns = 0; ns < 4; ns++) {
    int o = n0 + ns * 16 + col;
    float bias = bcat[o];
    if (isqk) {
#pragma unroll
      for (int rg = 0; rg < 4; rg++) {
        int i = m0 + w * 16 + quad * 4 + rg;
        qk[((size_t)b * 4096 + i) * 256 + o] = (f16)(acc[ns][rg] + bias);
      }
    } else {
      int i = m0 + w * 16 + quad * 4;
      f16x4v pv;
#pragma unroll
      for (int rg = 0; rg < 4; rg++) pv[rg] = (f16)(acc[ns][rg] + bias);
      *(f16x4v*)&vv[((size_t)b * 256 + (o - 256)) * 4096 + i] = pv;
    }
  }
}

// ---------------- kernel 2: phase A — row max & sumexp ----------------
__global__ void __launch_bounds__(256, 2)
k_stats(const f16* __restrict__ qk, float* __restrict__ rowmax, float* __restrict__ rowsum) {
  constexpr int LDK = 136;  // 128 + 8 pad
  __shared__ f16 sQ[32 * LDK], sK[64 * LDK];
  __shared__ float sM[4][32], sL[4][32];
  int b = blockIdx.y, i0 = blockIdx.x * 32;
  int tid = threadIdx.x, lane = tid & 63, w = tid >> 6;
  int col = lane & 15, quad = lane >> 4, ko = quad * 8;
  {
    int r = tid >> 4, kk = (tid & 15) * 8;
#pragma unroll
    for (int rr = r; rr < 32; rr += 16)
      *(f16x8v*)&sQ[rr * LDK + kk] = *(const f16x8v*)&qk[((size_t)b * 4096 + i0 + rr) * 256 + kk];
  }
  float M[2][4], L[2][4];
#pragma unroll
  for (int is = 0; is < 2; is++)
#pragma unroll
    for (int rg = 0; rg < 4; rg++) { M[is][rg] = -1e30f; L[is][rg] = 0.f; }
  for (int j0 = 0; j0 < 4096; j0 += 64) {
    __syncthreads();
    {
      int r = tid >> 4, kk = (tid & 15) * 8;
#pragma unroll
      for (int rr = r; rr < 64; rr += 16)
        *(f16x8v*)&sK[rr * LDK + kk] =
            *(const f16x8v*)&qk[((size_t)b * 4096 + j0 + rr) * 256 + 128 + kk];
    }
    __syncthreads();
    int jrow = w * 16 + col;  // this wave's j slice
#pragma unroll
    for (int is = 0; is < 2; is++) {
      f32x4v s = {};
#pragma unroll
      for (int ks = 0; ks < 4; ks++) {
        f16x8v a = *(const f16x8v*)&sQ[(is * 16 + col) * LDK + ks * 32 + ko];
        f16x8v kb = *(const f16x8v*)&sK[jrow * LDK + ks * 32 + ko];
        s = mfma16(a, kb, s);
      }
#pragma unroll
      for (int rg = 0; rg < 4; rg++) {
        float sv = s[rg];
        float Mo = M[is][rg];
        float Mn = fmaxf(Mo, sv);
        L[is][rg] = L[is][rg] * __expf(Mo - Mn) + __expf(sv - Mn);
        M[is][rg] = Mn;
      }
    }
  }
  // combine across the 16 lanes of each quad-group (j slices), then across waves
#pragma unroll
  for (int is = 0; is < 2; is++)
#pragma unroll
    for (int rg = 0; rg < 4; rg++) {
      float m = M[is][rg], l = L[is][rg];
#pragma unroll
      for (int d = 1; d < 16; d <<= 1) {
        float mo = __shfl_xor(m, d, 64);
        float lo = __shfl_xor(l, d, 64);
        float mn = fmaxf(m, mo);
        l = l * __expf(m - mn) + lo * __expf(mo - mn);
        m = mn;
      }
      M[is][rg] = m; L[is][rg] = l;
    }
  if (col == 0) {
#pragma unroll
    for (int is = 0; is < 2; is++)
#pragma unroll
      for (int rg = 0; rg < 4; rg++) {
        sM[w][is * 16 + quad * 4 + rg] = M[is][rg];
        sL[w][is * 16 + quad * 4 + rg] = L[is][rg];
      }
  }
  __syncthreads();
  if (tid < 32) {
    float m = sM[0][tid], l = sL[0][tid];
#pragma unroll
    for (int ww = 1; ww < 4; ww++) {
      float mo = sM[ww][tid], lo = sL[ww][tid];
      float mn = fmaxf(m, mo);
      l = l * __expf(m - mn) + lo * __expf(mo - mn);
      m = mn;
    }
    rowmax[(size_t)b * 4096 + i0 + tid] = m;
    rowsum[(size_t)b * 4096 + i0 + tid] = l;
  }
}

// ---------------- kernel 3: fold 1/rowsum into V ----------------
__global__ void k_scalev(f16* __restrict__ vv, const float* __restrict__ rowsum) {
  size_t idx = ((size_t)blockIdx.x * 256 + threadIdx.x) * 8;
  int i = (int)(idx & 4095);
  int b = (int)(idx >> 20);  // idx/(256*4096)
  f16x8v v = *(f16x8v*)&vv[idx];
  const float* rs = rowsum + ((size_t)b << 12) + i;
  f16x8v o;
#pragma unroll
  for (int t = 0; t < 8; t++) o[t] = (f16)((float)v[t] * (1.0f / rs[t]));
  *(f16x8v*)&vv[idx] = o;
}

// ---------------- kernel 4: phase B — S recompute, P=exp, AV, residual ----------------
__global__ void __launch_bounds__(256, 2)
k_attn_av(const f16* __restrict__ qk, const f16* __restrict__ vv,
          const float* __restrict__ rowmax, const float* __restrict__ x,
          const float* __restrict__ gamma, float* __restrict__ out) {
  constexpr int LDK = 136, LDV = 72, LDP = 72;
  __shared__ f16 sK[64 * LDK];   // k rows for this j-tile (fixed)
  __shared__ f16 sQ[64 * LDK];   // q rows for current i-chunk
  __shared__ f16 sV[128 * LDV];  // v' rows (this c-half) x i-chunk
  __shared__ f16 sP[64 * LDP];   // P^T: rows j, cols i (B-operand layout for AV)
  __shared__ float sRM[64];
  int b = blockIdx.z, cb = blockIdx.y, j0 = blockIdx.x * 64;
  int tid = threadIdx.x, lane = tid & 63, w = tid >> 6;
  int col = lane & 15, quad = lane >> 4, ko = quad * 8;
  {
    int r = tid >> 4, kk = (tid & 15) * 8;
#pragma unroll
    for (int rr = r; rr < 64; rr += 16)
      *(f16x8v*)&sK[rr * LDK + kk] =
          *(const f16x8v*)&qk[((size_t)b * 4096 + j0 + rr) * 256 + 128 + kk];
  }
  f32x4v acc[2][4] = {};
  for (int i0 = 0; i0 < 4096; i0 += 64) {
    __syncthreads();
    {
      int r = tid >> 4, kk = (tid & 15) * 8;
#pragma unroll
      for (int rr = r; rr < 64; rr += 16)
        *(f16x8v*)&sQ[rr * LDK + kk] =
            *(const f16x8v*)&qk[((size_t)b * 4096 + i0 + rr) * 256 + kk];
      int r2 = tid >> 4, c4 = (tid & 15) * 4;
#pragma unroll
      for (int rr = r2; rr < 128; rr += 16)
        *(f16x4v*)&sV[rr * LDV + c4] =
            *(const f16x4v*)&vv[((size_t)b * 256 + cb * 128 + rr) * 4096 + i0 + c4];
      if (tid < 64) sRM[tid] = rowmax[(size_t)b * 4096 + i0 + tid];
    }
    __syncthreads();
    // S: wave w -> i rows [w*16, w*16+16) x all 64 j ; then P^T -> LDS
    int irow = w * 16 + col;
#pragma unroll
    for (int js = 0; js < 4; js++) {
      f32x4v s = {};
#pragma unroll
      for (int ks = 0; ks < 4; ks++) {
        f16x8v a = *(const f16x8v*)&sQ[irow * LDK + ks * 32 + ko];
        f16x8v kb = *(const f16x8v*)&sK[(js * 16 + col) * LDK + ks * 32 + ko];
        s = mfma16(a, kb, s);
      }
      f16x4v pw;
#pragma unroll
      for (int rg = 0; rg < 4; rg++)
        pw[rg] = (f16)__expf(s[rg] - sRM[w * 16 + quad * 4 + rg]);
      *(f16x4v*)&sP[(js * 16 + col) * LDP + w * 16 + quad * 4] = pw;
    }
    __syncthreads();
    // AV: wave w -> c rows [w*32, w*32+32) x 64 j, contract i-chunk (K=64)
#pragma unroll
    for (int ks = 0; ks < 2; ks++) {
#pragma unroll
      for (int cs = 0; cs < 2; cs++) {
        f16x8v a = *(const f16x8v*)&sV[(w * 32 + cs * 16 + col) * LDV + ks * 32 + ko];
#pragma unroll
        for (int js = 0; js < 4; js++) {
          f16x8v pb = *(const f16x8v*)&sP[(js * 16 + col) * LDP + ks * 32 + ko];
          acc[cs][js] = mfma16(a, pb, acc[cs][js]);
        }
      }
    }
  }
  float g = gamma[0];
#pragma unroll
  for (int cs = 0; cs < 2; cs++)
#pragma unroll
    for (int js = 0; js < 4; js++) {
      int c = cb * 128 + w * 32 + cs * 16 + quad * 4;
      int j = j0 + js * 16 + col;
#pragma unroll
      for (int rg = 0; rg < 4; rg++) {
        size_t off = ((size_t)b * 256 + c + rg) * 4096 + j;
        out[off] = g * acc[cs][js][rg] + x[off];
      }
    }
}

extern "C" void kernel_launch(void* const* d_in, const int* in_sizes, int n_in,
                              void* d_out, int out_size, void* d_ws, size_t ws_size,
                              hipStream_t stream) {
  (void)in_sizes; (void)n_in; (void)out_size; (void)ws_size;
  const float* x  = (const float*)d_in[0];
  const float* wq = (const float*)d_in[1];
  const float* bq = (const float*)d_in[2];
  const float* wk = (const float*)d_in[3];
  const float* bk = (const float*)d_in[4];
  const float* wv = (const float*)d_in[5];
  const float* bv = (const float*)d_in[6];
  const float* gm = (const float*)d_in[7];
  float* out = (float*)d_out;

  char* ws = (char*)d_ws;
  const size_t SZ = (size_t)4 * 4096 * 256 * 2;  // 8 MB per f16 [B][4096][256]-ish array
  f16* xh = (f16*)(ws);
  f16* xl = (f16*)(ws + SZ);
  f16* qk = (f16*)(ws + 2 * SZ);          // [b][i][0:128]=q, [128:256]=k
  f16* vv = (f16*)(ws + 3 * SZ);          // [b][c][i]
  f16* wh = (f16*)(ws + 4 * SZ);          // [512][256]
  f16* wl = (f16*)(ws + 4 * SZ + 262144);
  float* bcat   = (float*)(ws + 4 * SZ + 524288);
  float* rowmax = (float*)(ws + 4 * SZ + 524288 + 4096);
  float* rowsum = (float*)(ws + 4 * SZ + 524288 + 4096 + 65536);
  // total ws use: 32 MB + 528 KB + 132 KB

  hipLaunchKernelGGL(k_wsplit, dim3(512), dim3(256), 0, stream, wq, bq, wk, bk, wv, bv, wh, wl, bcat);
  hipLaunchKernelGGL(k_xsplit, dim3(64, 4, 4), dim3(256), 0, stream, x, xh, xl);
  hipLaunchKernelGGL(k_proj, dim3(8, 64, 4), dim3(256), 0, stream, xh, xl, wh, wl, bcat, qk, vv);
  hipLaunchKernelGGL(k_stats, dim3(128, 4), dim3(256), 0, stream, qk, rowmax, rowsum);
  hipLaunchKernelGGL(k_scalev, dim3(2048), dim3(256), 0, stream, vv, rowsum);
  hipLaunchKernelGGL(k_attn_av, dim3(64, 2, 4), dim3(256), 0, stream, qk, vv, rowmax, x, gm, out);
}

// Round 2
// 310.405 us; speedup vs baseline: 1.4452x; 1.4452x over previous
//
#include <hip/hip_runtime.h>

// ConvSelfAttentionModule: B=4, C=256, CQK=128, N=4096 (64x64), fp32 in/out.
// Pipeline:
//   k_wsplit  : split fp32 weights -> f16 hi/lo
//   k_xsplit  : transpose+split x[b][c][n] -> xT hi/lo [b][n][c] f16
//   k_proj    : split-f16 MFMA GEMM -> qk[b][i][0:128]=q,[128:256]=k ; vv[b][c][i]
//   k_stats   : per-row max & sumexp of S = q.k^T (streaming)
//   k_scalev  : vv *= 1/rowsum
//   k_pmake   : S tiles (K=128 single-shot, global_load_lds), P=exp(S-m) f16,
//               LDS transpose -> P_T[b][j][i] (coalesced 16B stores)
//   k_av      : NT GEMM out[c][j] = gamma * sum_i vv'[c][i]*P_T[j][i] + x
// Fallback (ws too small): R1's fused k_attn_av.

typedef _Float16 f16;
typedef _Float16 f16x4v __attribute__((ext_vector_type(4)));
typedef _Float16 f16x8v __attribute__((ext_vector_type(8)));
typedef float f32x4v __attribute__((ext_vector_type(4)));

static __device__ __forceinline__ f32x4v mfma16(f16x8v a, f16x8v b, f32x4v c) {
  // D[m][n]: a-frag m=lane&15,k=quad*8+j; b-frag (B^T rows) n=lane&15,k=quad*8+j;
  // D: col(n)=lane&15, row(m)=quad*4+reg
  return __builtin_amdgcn_mfma_f32_16x16x32_f16(a, b, c, 0, 0, 0);
}

#define AS1q __attribute__((address_space(1)))
#define AS3q __attribute__((address_space(3)))
static __device__ __forceinline__ void gl_lds16(const void* g, void* l) {
  // 16B per lane; LDS dest = wave-uniform base + lane*16
  __builtin_amdgcn_global_load_lds((const AS1q unsigned int*)g,
                                   (AS3q unsigned int*)l, 16, 0, 0);
}

// ---------------- kernel 0a: weight split ----------------
__global__ void k_wsplit(const float* __restrict__ wq, const float* __restrict__ bq,
                         const float* __restrict__ wk, const float* __restrict__ bk,
                         const float* __restrict__ wv, const float* __restrict__ bv,
                         f16* __restrict__ wh, f16* __restrict__ wl, float* __restrict__ bcat) {
  int o = blockIdx.x;
  int c = threadIdx.x;
  const float* wrow; float bias;
  if (o < 128)      { wrow = wq + (size_t)o * 256;        bias = bq[o]; }
  else if (o < 256) { wrow = wk + (size_t)(o - 128) * 256; bias = bk[o - 128]; }
  else              { wrow = wv + (size_t)(o - 256) * 256; bias = bv[o - 256]; }
  float v = wrow[c];
  f16 h = (f16)v;
  wh[(size_t)o * 256 + c] = h;
  wl[(size_t)o * 256 + c] = (f16)(v - (float)h);
  if (c == 0) bcat[o] = bias;
}

// ---------------- kernel 0b: x transpose + split ----------------
__global__ void k_xsplit(const float* __restrict__ x, f16* __restrict__ xh, f16* __restrict__ xl) {
  __shared__ float t[64][65];
  int b = blockIdx.z, c0 = blockIdx.y * 64, n0 = blockIdx.x * 64;
  int tx = threadIdx.x & 63, ty = threadIdx.x >> 6;
  const float* xb = x + ((size_t)b * 256 + c0) * 4096 + n0;
#pragma unroll
  for (int r = ty; r < 64; r += 4) t[r][tx] = xb[(size_t)r * 4096 + tx];
  __syncthreads();
  f16* dh = xh + ((size_t)b * 4096 + n0) * 256 + c0;
  f16* dl = xl + ((size_t)b * 4096 + n0) * 256 + c0;
#pragma unroll
  for (int r = ty; r < 64; r += 4) {
    float v = t[tx][r];
    f16 h = (f16)v;
    dh[(size_t)r * 256 + tx] = h;
    dl[(size_t)r * 256 + tx] = (f16)(v - (float)h);
  }
}

// ---------------- kernel 1: projections (split-f16 NT GEMM) ----------------
__global__ void __launch_bounds__(256, 2)
k_proj(const f16* __restrict__ xh, const f16* __restrict__ xl,
       const f16* __restrict__ wh, const f16* __restrict__ wl,
       const float* __restrict__ bcat, f16* __restrict__ qk, f16* __restrict__ vv) {
  constexpr int LDK = 40;
  __shared__ f16 sAh[64 * LDK], sAl[64 * LDK], sWh[64 * LDK], sWl[64 * LDK];
  int b = blockIdx.z, m0 = blockIdx.y * 64, n0 = blockIdx.x * 64;
  int tid = threadIdx.x, lane = tid & 63, w = tid >> 6;
  int col = lane & 15, quad = lane >> 4, ko = quad * 8;
  const f16* Ah = xh + ((size_t)b * 4096 + m0) * 256;
  const f16* Al = xl + ((size_t)b * 4096 + m0) * 256;
  const f16* Wh = wh + (size_t)n0 * 256;
  const f16* Wl = wl + (size_t)n0 * 256;
  f32x4v acc[4] = {};
  for (int k0 = 0; k0 < 256; k0 += 32) {
    __syncthreads();
    {
      int r = tid >> 3, kk = (tid & 7) * 4;
#pragma unroll
      for (int rr = r; rr < 64; rr += 32) {
        *(f16x4v*)&sAh[rr * LDK + kk] = *(const f16x4v*)&Ah[(size_t)rr * 256 + k0 + kk];
        *(f16x4v*)&sAl[rr * LDK + kk] = *(const f16x4v*)&Al[(size_t)rr * 256 + k0 + kk];
        *(f16x4v*)&sWh[rr * LDK + kk] = *(const f16x4v*)&Wh[(size_t)rr * 256 + k0 + kk];
        *(f16x4v*)&sWl[rr * LDK + kk] = *(const f16x4v*)&Wl[(size_t)rr * 256 + k0 + kk];
      }
    }
    __syncthreads();
    int mrow = w * 16 + col;
    f16x8v ah = *(const f16x8v*)&sAh[mrow * LDK + ko];
    f16x8v al = *(const f16x8v*)&sAl[mrow * LDK + ko];
#pragma unroll
    for (int ns = 0; ns < 4; ns++) {
      int nrow = ns * 16 + col;
      f16x8v bh = *(const f16x8v*)&sWh[nrow * LDK + ko];
      f16x8v bl = *(const f16x8v*)&sWl[nrow * LDK + ko];
      acc[ns] = mfma16(al, bh, acc[ns]);
      acc[ns] = mfma16(ah, bl, acc[ns]);
      acc[ns] = mfma16(ah, bh, acc[ns]);
    }
  }
  bool isqk = (n0 < 256);
#pragma unroll
  for (int ns = 0; ns < 4; ns++) {
    int o = n0 + ns * 16 + col;
    float bias = bcat[o];
    if (isqk) {
#pragma unroll
      for (int rg = 0; rg < 4; rg++) {
        int i = m0 + w * 16 + quad * 4 + rg;
        qk[((size_t)b * 4096 + i) * 256 + o] = (f16)(acc[ns][rg] + bias);
      }
    } else {
      int i = m0 + w * 16 + quad * 4;
      f16x4v pv;
#pragma unroll
      for (int rg = 0; rg < 4; rg++) pv[rg] = (f16)(acc[ns][rg] + bias);
      *(f16x4v*)&vv[((size_t)b * 256 + (o - 256)) * 4096 + i] = pv;
    }
  }
}

// ---------------- kernel 2: phase A — row max & sumexp ----------------
__global__ void __launch_bounds__(256, 2)
k_stats(const f16* __restrict__ qk, float* __restrict__ rowmax, float* __restrict__ rowsum) {
  constexpr int LDK = 136;
  __shared__ f16 sQ[32 * LDK], sK[64 * LDK];
  __shared__ float sM[4][32], sL[4][32];
  int b = blockIdx.y, i0 = blockIdx.x * 32;
  int tid = threadIdx.x, lane = tid & 63, w = tid >> 6;
  int col = lane & 15, quad = lane >> 4, ko = quad * 8;
  {
    int r = tid >> 4, kk = (tid & 15) * 8;
#pragma unroll
    for (int rr = r; rr < 32; rr += 16)
      *(f16x8v*)&sQ[rr * LDK + kk] = *(const f16x8v*)&qk[((size_t)b * 4096 + i0 + rr) * 256 + kk];
  }
  float M[2][4], L[2][4];
#pragma unroll
  for (int is = 0; is < 2; is++)
#pragma unroll
    for (int rg = 0; rg < 4; rg++) { M[is][rg] = -1e30f; L[is][rg] = 0.f; }
  for (int j0 = 0; j0 < 4096; j0 += 64) {
    __syncthreads();
    {
      int r = tid >> 4, kk = (tid & 15) * 8;
#pragma unroll
      for (int rr = r; rr < 64; rr += 16)
        *(f16x8v*)&sK[rr * LDK + kk] =
            *(const f16x8v*)&qk[((size_t)b * 4096 + j0 + rr) * 256 + 128 + kk];
    }
    __syncthreads();
    int jrow = w * 16 + col;
#pragma unroll
    for (int is = 0; is < 2; is++) {
      f32x4v s = {};
#pragma unroll
      for (int ks = 0; ks < 4; ks++) {
        f16x8v a = *(const f16x8v*)&sQ[(is * 16 + col) * LDK + ks * 32 + ko];
        f16x8v kb = *(const f16x8v*)&sK[jrow * LDK + ks * 32 + ko];
        s = mfma16(a, kb, s);
      }
#pragma unroll
      for (int rg = 0; rg < 4; rg++) {
        float sv = s[rg];
        float Mo = M[is][rg];
        float Mn = fmaxf(Mo, sv);
        L[is][rg] = L[is][rg] * __expf(Mo - Mn) + __expf(sv - Mn);
        M[is][rg] = Mn;
      }
    }
  }
#pragma unroll
  for (int is = 0; is < 2; is++)
#pragma unroll
    for (int rg = 0; rg < 4; rg++) {
      float m = M[is][rg], l = L[is][rg];
#pragma unroll
      for (int d = 1; d < 16; d <<= 1) {
        float mo = __shfl_xor(m, d, 64);
        float lo = __shfl_xor(l, d, 64);
        float mn = fmaxf(m, mo);
        l = l * __expf(m - mn) + lo * __expf(mo - mn);
        m = mn;
      }
      M[is][rg] = m; L[is][rg] = l;
    }
  if (col == 0) {
#pragma unroll
    for (int is = 0; is < 2; is++)
#pragma unroll
      for (int rg = 0; rg < 4; rg++) {
        sM[w][is * 16 + quad * 4 + rg] = M[is][rg];
        sL[w][is * 16 + quad * 4 + rg] = L[is][rg];
      }
  }
  __syncthreads();
  if (tid < 32) {
    float m = sM[0][tid], l = sL[0][tid];
#pragma unroll
    for (int ww = 1; ww < 4; ww++) {
      float mo = sM[ww][tid], lo = sL[ww][tid];
      float mn = fmaxf(m, mo);
      l = l * __expf(m - mn) + lo * __expf(mo - mn);
      m = mn;
    }
    rowmax[(size_t)b * 4096 + i0 + tid] = m;
    rowsum[(size_t)b * 4096 + i0 + tid] = l;
  }
}

// ---------------- kernel 3: fold 1/rowsum into V ----------------
__global__ void k_scalev(f16* __restrict__ vv, const float* __restrict__ rowsum) {
  size_t idx = ((size_t)blockIdx.x * 256 + threadIdx.x) * 8;
  int i = (int)(idx & 4095);
  int b = (int)(idx >> 20);
  f16x8v v = *(f16x8v*)&vv[idx];
  const float* rs = rowsum + ((size_t)b << 12) + i;
  f16x8v o;
#pragma unroll
  for (int t = 0; t < 8; t++) o[t] = (f16)((float)v[t] * (1.0f / rs[t]));
  *(f16x8v*)&vv[idx] = o;
}

// ---------------- kernel 4a: P^T materialize ----------------
// Per block: S for (128 i) x (64 j), K=128 single-shot via global_load_lds,
// P = exp(S - m_i) -> LDS transpose -> P_T[b][j][i] coalesced.
__global__ void __launch_bounds__(256, 2)
k_pmake(const f16* __restrict__ qk, const float* __restrict__ rowmax,
        f16* __restrict__ P) {
  __shared__ char smem[49152];   // sQ [128][128] (32K) + sK [64][128] (16K)
  __shared__ float sRM[128];
  f16* sQ = (f16*)smem;
  f16* sK = (f16*)(smem + 32768);
  f16* sPT = (f16*)smem;         // [64][132] overlay after compute (16.9K)
  int b = blockIdx.z, i0 = blockIdx.y * 128, j0 = blockIdx.x * 64;
  int tid = threadIdx.x, l = tid & 63, w = tid >> 6;
  int col = l & 15, q = l >> 4;
  if (tid < 128) sRM[tid] = rowmax[(size_t)b * 4096 + i0 + tid];
  const f16* qb = qk + (size_t)b * 4096 * 256;
  // stage Q: 32 chunks of 1KB; LDS[r][phys8] = G[r][phys8 ^ (r&15)]
#pragma unroll
  for (int p = 0; p < 8; p++) {
    int ci = w * 8 + p;
    int r = ci * 4 + (l >> 4);
    int cb = (l & 15) ^ (r & 15);
    gl_lds16(qb + (size_t)(i0 + r) * 256 + cb * 8, smem + ci * 1024);
  }
  // stage K rows j: 16 chunks
#pragma unroll
  for (int p = 0; p < 4; p++) {
    int ci = w * 4 + p;
    int r = ci * 4 + (l >> 4);
    int cb = (l & 15) ^ (r & 15);
    gl_lds16(qb + (size_t)(j0 + r) * 256 + 128 + cb * 8, smem + 32768 + ci * 1024);
  }
  __syncthreads();
  f32x4v acc[2][4] = {};
#pragma unroll
  for (int ks = 0; ks < 4; ks++) {
    int phys = (ks * 4 + q) ^ col;  // row&15 == col for all frag rows
    f16x8v a[2], bb[4];
#pragma unroll
    for (int mt = 0; mt < 2; mt++)
      a[mt] = *(const f16x8v*)&sQ[(w * 32 + mt * 16 + col) * 128 + phys * 8];
#pragma unroll
    for (int nt = 0; nt < 4; nt++)
      bb[nt] = *(const f16x8v*)&sK[(nt * 16 + col) * 128 + phys * 8];
#pragma unroll
    for (int mt = 0; mt < 2; mt++)
#pragma unroll
      for (int nt = 0; nt < 4; nt++)
        acc[mt][nt] = mfma16(a[mt], bb[nt], acc[mt][nt]);
  }
  __syncthreads();  // everyone done with sQ/sK -> reuse as sPT
#pragma unroll
  for (int mt = 0; mt < 2; mt++) {
    int ib = w * 32 + mt * 16 + q * 4;  // local i of regs 0..3
    float m0_ = sRM[ib], m1_ = sRM[ib + 1], m2_ = sRM[ib + 2], m3_ = sRM[ib + 3];
#pragma unroll
    for (int nt = 0; nt < 4; nt++) {
      f16x4v pw;
      pw[0] = (f16)__expf(acc[mt][nt][0] - m0_);
      pw[1] = (f16)__expf(acc[mt][nt][1] - m1_);
      pw[2] = (f16)__expf(acc[mt][nt][2] - m2_);
      pw[3] = (f16)__expf(acc[mt][nt][3] - m3_);
      *(f16x4v*)&sPT[(nt * 16 + col) * 132 + ib] = pw;  // row j, i contiguous
    }
  }
  __syncthreads();
  f16* Pb = P + ((size_t)b * 4096 + j0) * 4096 + i0;
#pragma unroll
  for (int p = 0; p < 4; p++) {
    int slot = p * 256 + tid;
    int jr = slot >> 4, c16 = slot & 15;
    *(f16x8v*)&Pb[(size_t)jr * 4096 + c16 * 8] =
        *(const f16x8v*)&sPT[jr * 132 + c16 * 8];
  }
}

// ---------------- kernel 4b: AV GEMM + residual ----------------
// out[b][c][j] = gamma * sum_i vv'[b][c][i] * P_T[b][j][i] + x[b][c][j]
// M=256(c) split in 128-tiles, N=4096(j) in 64-tiles, K=4096(i), BK=64.
__global__ void __launch_bounds__(256, 2)
k_av(const f16* __restrict__ vv, const f16* __restrict__ P,
     const float* __restrict__ x, const float* __restrict__ gamma,
     float* __restrict__ out) {
  __shared__ char smem[24576];   // sA [128][64] 16K + sB [64][64] 8K, XOR-swizzled
  f16* sA = (f16*)smem;
  f16* sB = (f16*)(smem + 16384);
  int b = blockIdx.z, c0 = blockIdx.y * 128, j0 = blockIdx.x * 64;
  int tid = threadIdx.x, l = tid & 63, w = tid >> 6;
  int col = l & 15, q = l >> 4;
  const f16* Ab = vv + ((size_t)b * 256 + c0) * 4096;
  const f16* Bb = P + ((size_t)b * 4096 + j0) * 4096;
  f32x4v acc[2][4] = {};
  for (int k0 = 0; k0 < 4096; k0 += 64) {
    __syncthreads();
#pragma unroll
    for (int p = 0; p < 4; p++) {
      int ci = w * 4 + p;
      int r = ci * 8 + (l >> 3);
      int cb = (l & 7) ^ (r & 7);
      gl_lds16(Ab + (size_t)r * 4096 + k0 + cb * 8, smem + ci * 1024);
    }
#pragma unroll
    for (int p = 0; p < 2; p++) {
      int ci = w * 2 + p;
      int r = ci * 8 + (l >> 3);
      int cb = (l & 7) ^ (r & 7);
      gl_lds16(Bb + (size_t)r * 4096 + k0 + cb * 8, smem + 16384 + ci * 1024);
    }
    __syncthreads();
#pragma unroll
    for (int ks = 0; ks < 2; ks++) {
      int phys = (ks * 4 + q) ^ (col & 7);
      f16x8v a[2], bb[4];
#pragma unroll
      for (int mt = 0; mt < 2; mt++)
        a[mt] = *(const f16x8v*)&sA[(w * 32 + mt * 16 + col) * 64 + phys * 8];
#pragma unroll
      for (int nt = 0; nt < 4; nt++)
        bb[nt] = *(const f16x8v*)&sB[(nt * 16 + col) * 64 + phys * 8];
#pragma unroll
      for (int mt = 0; mt < 2; mt++)
#pragma unroll
        for (int nt = 0; nt < 4; nt++)
          acc[mt][nt] = mfma16(a[mt], bb[nt], acc[mt][nt]);
    }
  }
  float g = gamma[0];
#pragma unroll
  for (int mt = 0; mt < 2; mt++)
#pragma unroll
    for (int nt = 0; nt < 4; nt++) {
      int c = c0 + w * 32 + mt * 16 + q * 4;
      int j = j0 + nt * 16 + col;
#pragma unroll
      for (int rg = 0; rg < 4; rg++) {
        size_t off = ((size_t)b * 256 + c + rg) * 4096 + j;
        out[off] = g * acc[mt][nt][rg] + x[off];
      }
    }
}

// ---------------- fallback: R1 fused attn (if ws too small for P) ----------------
__global__ void __launch_bounds__(256, 2)
k_attn_av(const f16* __restrict__ qk, const f16* __restrict__ vv,
          const float* __restrict__ rowmax, const float* __restrict__ x,
          const float* __restrict__ gamma, float* __restrict__ out) {
  constexpr int LDK = 136, LDV = 72, LDP = 72;
  __shared__ f16 sK[64 * LDK];
  __shared__ f16 sQ[64 * LDK];
  __shared__ f16 sV[128 * LDV];
  __shared__ f16 sP[64 * LDP];
  __shared__ float sRM[64];
  int b = blockIdx.z, cb = blockIdx.y, j0 = blockIdx.x * 64;
  int tid = threadIdx.x, lane = tid & 63, w = tid >> 6;
  int col = lane & 15, quad = lane >> 4, ko = quad * 8;
  {
    int r = tid >> 4, kk = (tid & 15) * 8;
#pragma unroll
    for (int rr = r; rr < 64; rr += 16)
      *(f16x8v*)&sK[rr * LDK + kk] =
          *(const f16x8v*)&qk[((size_t)b * 4096 + j0 + rr) * 256 + 128 + kk];
  }
  f32x4v acc[2][4] = {};
  for (int i0 = 0; i0 < 4096; i0 += 64) {
    __syncthreads();
    {
      int r = tid >> 4, kk = (tid & 15) * 8;
#pragma unroll
      for (int rr = r; rr < 64; rr += 16)
        *(f16x8v*)&sQ[rr * LDK + kk] =
            *(const f16x8v*)&qk[((size_t)b * 4096 + i0 + rr) * 256 + kk];
      int r2 = tid >> 4, c4 = (tid & 15) * 4;
#pragma unroll
      for (int rr = r2; rr < 128; rr += 16)
        *(f16x4v*)&sV[rr * LDV + c4] =
            *(const f16x4v*)&vv[((size_t)b * 256 + cb * 128 + rr) * 4096 + i0 + c4];
      if (tid < 64) sRM[tid] = rowmax[(size_t)b * 4096 + i0 + tid];
    }
    __syncthreads();
    int irow = w * 16 + col;
#pragma unroll
    for (int js = 0; js < 4; js++) {
      f32x4v s = {};
#pragma unroll
      for (int ks = 0; ks < 4; ks++) {
        f16x8v a = *(const f16x8v*)&sQ[irow * LDK + ks * 32 + ko];
        f16x8v kb = *(const f16x8v*)&sK[(js * 16 + col) * LDK + ks * 32 + ko];
        s = mfma16(a, kb, s);
      }
      f16x4v pw;
#pragma unroll
      for (int rg = 0; rg < 4; rg++)
        pw[rg] = (f16)__expf(s[rg] - sRM[w * 16 + quad * 4 + rg]);
      *(f16x4v*)&sP[(js * 16 + col) * LDP + w * 16 + quad * 4] = pw;
    }
    __syncthreads();
#pragma unroll
    for (int ks = 0; ks < 2; ks++) {
#pragma unroll
      for (int cs = 0; cs < 2; cs++) {
        f16x8v a = *(const f16x8v*)&sV[(w * 32 + cs * 16 + col) * LDV + ks * 32 + ko];
#pragma unroll
        for (int js = 0; js < 4; js++) {
          f16x8v pb = *(const f16x8v*)&sP[(js * 16 + col) * LDP + ks * 32 + ko];
          acc[cs][js] = mfma16(a, pb, acc[cs][js]);
        }
      }
    }
  }
  float g = gamma[0];
#pragma unroll
  for (int cs = 0; cs < 2; cs++)
#pragma unroll
    for (int js = 0; js < 4; js++) {
      int c = cb * 128 + w * 32 + cs * 16 + quad * 4;
      int j = j0 + js * 16 + col;
#pragma unroll
      for (int rg = 0; rg < 4; rg++) {
        size_t off = ((size_t)b * 256 + c + rg) * 4096 + j;
        out[off] = g * acc[cs][js][rg] + x[off];
      }
    }
}

extern "C" void kernel_launch(void* const* d_in, const int* in_sizes, int n_in,
                              void* d_out, int out_size, void* d_ws, size_t ws_size,
                              hipStream_t stream) {
  (void)in_sizes; (void)n_in; (void)out_size;
  const float* x  = (const float*)d_in[0];
  const float* wq = (const float*)d_in[1];
  const float* bq = (const float*)d_in[2];
  const float* wk = (const float*)d_in[3];
  const float* bk = (const float*)d_in[4];
  const float* wv = (const float*)d_in[5];
  const float* bv = (const float*)d_in[6];
  const float* gm = (const float*)d_in[7];
  float* out = (float*)d_out;

  char* ws = (char*)d_ws;
  const size_t SZ = (size_t)4 * 4096 * 256 * 2;  // 8 MB
  f16* xh = (f16*)(ws);
  f16* xl = (f16*)(ws + SZ);
  f16* qk = (f16*)(ws + 2 * SZ);          // [b][i][0:128]=q, [128:256]=k
  f16* vv = (f16*)(ws + 3 * SZ);          // [b][c][i]
  f16* wh = (f16*)(ws + 4 * SZ);
  f16* wl = (f16*)(ws + 4 * SZ + 262144);
  float* bcat   = (float*)(ws + 4 * SZ + 524288);
  float* rowmax = (float*)(ws + 4 * SZ + 524288 + 4096);
  float* rowsum = (float*)(ws + 4 * SZ + 524288 + 4096 + 65536);
  const size_t OFF_P = 4 * SZ + (1 << 20);           // 34.6 MB
  const size_t P_BYTES = (size_t)4 * 4096 * 4096 * 2; // 128 MB
  f16* Pt = (f16*)(ws + OFF_P);
  bool big = (ws_size >= OFF_P + P_BYTES);

  hipLaunchKernelGGL(k_wsplit, dim3(512), dim3(256), 0, stream, wq, bq, wk, bk, wv, bv, wh, wl, bcat);
  hipLaunchKernelGGL(k_xsplit, dim3(64, 4, 4), dim3(256), 0, stream, x, xh, xl);
  hipLaunchKernelGGL(k_proj, dim3(8, 64, 4), dim3(256), 0, stream, xh, xl, wh, wl, bcat, qk, vv);
  hipLaunchKernelGGL(k_stats, dim3(128, 4), dim3(256), 0, stream, qk, rowmax, rowsum);
  hipLaunchKernelGGL(k_scalev, dim3(2048), dim3(256), 0, stream, vv, rowsum);
  if (big) {
    hipLaunchKernelGGL(k_pmake, dim3(64, 32, 4), dim3(256), 0, stream, qk, rowmax, Pt);
    hipLaunchKernelGGL(k_av, dim3(64, 2, 4), dim3(256), 0, stream, vv, Pt, x, gm, out);
  } else {
    hipLaunchKernelGGL(k_attn_av, dim3(64, 2, 4), dim3(256), 0, stream, qk, vv, rowmax, x, gm, out);
  }
}

// Round 3
// 223.371 us; speedup vs baseline: 2.0084x; 1.3896x over previous
//
#include <hip/hip_runtime.h>
#include <hip/hip_bf16.h>

// ConvSelfAttentionModule: B=4, C=256, CQK=128, N=4096 (64x64), fp32 in/out.
// Pipeline (R3: no separate stats pass — S computed exactly ONCE):
//   k_wsplit : split fp32 weights -> f16 hi/lo
//   k_xsplit : transpose+split x[b][c][n] -> xT hi/lo [b][n][c] f16
//   k_proj   : split-f16 MFMA GEMM -> qk[b][i][0:128]=q,[128:256]=k ; vv[b][c][i] f16
//   k_pmake  : S tiles (K=128 single-shot via global_load_lds), P=exp(S) RAW in
//              bf16 (bf16 range ~e^88 >> max score ~e^50, no max-sub needed),
//              write P_T[b][j][i]; per-tile column sums -> partial[b][jblk][i]
//   k_rsum   : rowsum[b][i] = sum_jblk partial
//   k_scalev : vv bf16 <- f16 vv / rowsum  (normalization folded into V;
//              v/rowsum ~ 1e-12 is normal-range in bf16, underflows f16)
//   k_av     : bf16 NT GEMM out[c][j] = gamma * sum_i vv'[c][i]*P_T[j][i] + x
// ws layout: P (128MB) overlaps xh/xl lifetime; peak 148.6 MB (<161 MB proven).

typedef _Float16 f16;
typedef _Float16 f16x4v __attribute__((ext_vector_type(4)));
typedef _Float16 f16x8v __attribute__((ext_vector_type(8)));
typedef float f32x4v __attribute__((ext_vector_type(4)));
typedef unsigned short u16;
typedef unsigned short u16x4v __attribute__((ext_vector_type(4)));
typedef unsigned short u16x8v __attribute__((ext_vector_type(8)));
typedef short s16x8v __attribute__((ext_vector_type(8)));

static __device__ __forceinline__ f32x4v mfma16(f16x8v a, f16x8v b, f32x4v c) {
  // D[m][n]: a-frag m=lane&15,k=quad*8+j; b-frag (B^T rows) n=lane&15,k=quad*8+j;
  // D: col(n)=lane&15, row(m)=quad*4+reg
  return __builtin_amdgcn_mfma_f32_16x16x32_f16(a, b, c, 0, 0, 0);
}
static __device__ __forceinline__ f32x4v mfma_bf(s16x8v a, s16x8v b, f32x4v c) {
  return __builtin_amdgcn_mfma_f32_16x16x32_bf16(a, b, c, 0, 0, 0);
}
static __device__ __forceinline__ u16 f2bf(float f) {
  union { __hip_bfloat16 h; u16 u; } cv;
  cv.h = __float2bfloat16(f);  // RNE
  return cv.u;
}

#define AS1q __attribute__((address_space(1)))
#define AS3q __attribute__((address_space(3)))
static __device__ __forceinline__ void gl_lds16(const void* g, void* l) {
  // 16B per lane; LDS dest = wave-uniform base + lane*16
  __builtin_amdgcn_global_load_lds((const AS1q unsigned int*)g,
                                   (AS3q unsigned int*)l, 16, 0, 0);
}

// ---------------- kernel 0a: weight split ----------------
__global__ void k_wsplit(const float* __restrict__ wq, const float* __restrict__ bq,
                         const float* __restrict__ wk, const float* __restrict__ bk,
                         const float* __restrict__ wv, const float* __restrict__ bv,
                         f16* __restrict__ wh, f16* __restrict__ wl, float* __restrict__ bcat) {
  int o = blockIdx.x;
  int c = threadIdx.x;
  const float* wrow; float bias;
  if (o < 128)      { wrow = wq + (size_t)o * 256;        bias = bq[o]; }
  else if (o < 256) { wrow = wk + (size_t)(o - 128) * 256; bias = bk[o - 128]; }
  else              { wrow = wv + (size_t)(o - 256) * 256; bias = bv[o - 256]; }
  float v = wrow[c];
  f16 h = (f16)v;
  wh[(size_t)o * 256 + c] = h;
  wl[(size_t)o * 256 + c] = (f16)(v - (float)h);
  if (c == 0) bcat[o] = bias;
}

// ---------------- kernel 0b: x transpose + split ----------------
__global__ void k_xsplit(const float* __restrict__ x, f16* __restrict__ xh, f16* __restrict__ xl) {
  __shared__ float t[64][65];
  int b = blockIdx.z, c0 = blockIdx.y * 64, n0 = blockIdx.x * 64;
  int tx = threadIdx.x & 63, ty = threadIdx.x >> 6;
  const float* xb = x + ((size_t)b * 256 + c0) * 4096 + n0;
#pragma unroll
  for (int r = ty; r < 64; r += 4) t[r][tx] = xb[(size_t)r * 4096 + tx];
  __syncthreads();
  f16* dh = xh + ((size_t)b * 4096 + n0) * 256 + c0;
  f16* dl = xl + ((size_t)b * 4096 + n0) * 256 + c0;
#pragma unroll
  for (int r = ty; r < 64; r += 4) {
    float v = t[tx][r];
    f16 h = (f16)v;
    dh[(size_t)r * 256 + tx] = h;
    dl[(size_t)r * 256 + tx] = (f16)(v - (float)h);
  }
}

// ---------------- kernel 1: projections (split-f16 NT GEMM) ----------------
__global__ void __launch_bounds__(256, 2)
k_proj(const f16* __restrict__ xh, const f16* __restrict__ xl,
       const f16* __restrict__ wh, const f16* __restrict__ wl,
       const float* __restrict__ bcat, f16* __restrict__ qk, f16* __restrict__ vv) {
  constexpr int LDK = 40;
  __shared__ f16 sAh[64 * LDK], sAl[64 * LDK], sWh[64 * LDK], sWl[64 * LDK];
  int b = blockIdx.z, m0 = blockIdx.y * 64, n0 = blockIdx.x * 64;
  int tid = threadIdx.x, lane = tid & 63, w = tid >> 6;
  int col = lane & 15, quad = lane >> 4, ko = quad * 8;
  const f16* Ah = xh + ((size_t)b * 4096 + m0) * 256;
  const f16* Al = xl + ((size_t)b * 4096 + m0) * 256;
  const f16* Wh = wh + (size_t)n0 * 256;
  const f16* Wl = wl + (size_t)n0 * 256;
  f32x4v acc[4] = {};
  for (int k0 = 0; k0 < 256; k0 += 32) {
    __syncthreads();
    {
      int r = tid >> 3, kk = (tid & 7) * 4;
#pragma unroll
      for (int rr = r; rr < 64; rr += 32) {
        *(f16x4v*)&sAh[rr * LDK + kk] = *(const f16x4v*)&Ah[(size_t)rr * 256 + k0 + kk];
        *(f16x4v*)&sAl[rr * LDK + kk] = *(const f16x4v*)&Al[(size_t)rr * 256 + k0 + kk];
        *(f16x4v*)&sWh[rr * LDK + kk] = *(const f16x4v*)&Wh[(size_t)rr * 256 + k0 + kk];
        *(f16x4v*)&sWl[rr * LDK + kk] = *(const f16x4v*)&Wl[(size_t)rr * 256 + k0 + kk];
      }
    }
    __syncthreads();
    int mrow = w * 16 + col;
    f16x8v ah = *(const f16x8v*)&sAh[mrow * LDK + ko];
    f16x8v al = *(const f16x8v*)&sAl[mrow * LDK + ko];
#pragma unroll
    for (int ns = 0; ns < 4; ns++) {
      int nrow = ns * 16 + col;
      f16x8v bh = *(const f16x8v*)&sWh[nrow * LDK + ko];
      f16x8v bl = *(const f16x8v*)&sWl[nrow * LDK + ko];
      acc[ns] = mfma16(al, bh, acc[ns]);
      acc[ns] = mfma16(ah, bl, acc[ns]);
      acc[ns] = mfma16(ah, bh, acc[ns]);
    }
  }
  bool isqk = (n0 < 256);
#pragma unroll
  for (int ns = 0; ns < 4; ns++) {
    int o = n0 + ns * 16 + col;
    float bias = bcat[o];
    if (isqk) {
#pragma unroll
      for (int rg = 0; rg < 4; rg++) {
        int i = m0 + w * 16 + quad * 4 + rg;
        qk[((size_t)b * 4096 + i) * 256 + o] = (f16)(acc[ns][rg] + bias);
      }
    } else {
      int i = m0 + w * 16 + quad * 4;
      f16x4v pv;
#pragma unroll
      for (int rg = 0; rg < 4; rg++) pv[rg] = (f16)(acc[ns][rg] + bias);
      *(f16x4v*)&vv[((size_t)b * 256 + (o - 256)) * 4096 + i] = pv;
    }
  }
}

// ---------------- kernel 2: P^T materialize + partial column sums ----------------
// Per block: S for (128 i) x (64 j), K=128 single-shot via global_load_lds.
// P = exp(S) raw (bf16) -> LDS transpose -> P_T[b][j][i] coalesced.
// partial[b][jblk][i] = sum over this tile's 64 j of exp(s_ij).
__global__ void __launch_bounds__(256, 2)
k_pmake(const f16* __restrict__ qk, u16* __restrict__ P, float* __restrict__ partial) {
  __shared__ char smem[49152];   // sQ [128][128] (32K) + sK [64][128] (16K)
  f16* sQ = (f16*)smem;
  f16* sK = (f16*)(smem + 32768);
  u16* sPT = (u16*)smem;         // [64][132] overlay after compute (16.9K)
  int b = blockIdx.z, i0 = blockIdx.y * 128, j0 = blockIdx.x * 64;
  int tid = threadIdx.x, l = tid & 63, w = tid >> 6;
  int col = l & 15, q = l >> 4;
  const f16* qb = qk + (size_t)b * 4096 * 256;
  // stage Q: 32 chunks of 1KB; LDS[r][phys8] = G[r][phys8 ^ (r&15)]
#pragma unroll
  for (int p = 0; p < 8; p++) {
    int ci = w * 8 + p;
    int r = ci * 4 + (l >> 4);
    int cb = (l & 15) ^ (r & 15);
    gl_lds16(qb + (size_t)(i0 + r) * 256 + cb * 8, smem + ci * 1024);
  }
  // stage K rows j: 16 chunks
#pragma unroll
  for (int p = 0; p < 4; p++) {
    int ci = w * 4 + p;
    int r = ci * 4 + (l >> 4);
    int cb = (l & 15) ^ (r & 15);
    gl_lds16(qb + (size_t)(j0 + r) * 256 + 128 + cb * 8, smem + 32768 + ci * 1024);
  }
  __syncthreads();
  f32x4v acc[2][4] = {};
#pragma unroll
  for (int ks = 0; ks < 4; ks++) {
    int phys = (ks * 4 + q) ^ col;  // row&15 == col for all frag rows
    f16x8v a[2], bb[4];
#pragma unroll
    for (int mt = 0; mt < 2; mt++)
      a[mt] = *(const f16x8v*)&sQ[(w * 32 + mt * 16 + col) * 128 + phys * 8];
#pragma unroll
    for (int nt = 0; nt < 4; nt++)
      bb[nt] = *(const f16x8v*)&sK[(nt * 16 + col) * 128 + phys * 8];
#pragma unroll
    for (int mt = 0; mt < 2; mt++)
#pragma unroll
      for (int nt = 0; nt < 4; nt++)
        acc[mt][nt] = mfma16(a[mt], bb[nt], acc[mt][nt]);
  }
  // exp (raw, fp32) — keep for reduction; bf16 into sPT
  float pe[2][4][4];
#pragma unroll
  for (int mt = 0; mt < 2; mt++)
#pragma unroll
    for (int nt = 0; nt < 4; nt++)
#pragma unroll
      for (int rg = 0; rg < 4; rg++)
        pe[mt][nt][rg] = __expf(acc[mt][nt][rg]);
  __syncthreads();  // everyone done with sQ/sK -> reuse as sPT
#pragma unroll
  for (int mt = 0; mt < 2; mt++) {
    int ib = w * 32 + mt * 16 + q * 4;  // local i of regs 0..3
#pragma unroll
    for (int nt = 0; nt < 4; nt++) {
      u16x4v pw;
#pragma unroll
      for (int rg = 0; rg < 4; rg++) pw[rg] = f2bf(pe[mt][nt][rg]);
      *(u16x4v*)&sPT[(nt * 16 + col) * 132 + ib] = pw;  // row j, i contiguous
    }
  }
  // partial column sums: sum over nt (in-lane) then over 16 cols (shuffle)
#pragma unroll
  for (int mt = 0; mt < 2; mt++) {
    f32x4v cs;
#pragma unroll
    for (int rg = 0; rg < 4; rg++) {
      float t = pe[mt][0][rg] + pe[mt][1][rg] + pe[mt][2][rg] + pe[mt][3][rg];
#pragma unroll
      for (int d = 1; d < 16; d <<= 1) t += __shfl_xor(t, d, 64);
      cs[rg] = t;
    }
    if (col == 0) {
      size_t base = ((size_t)b * 64 + blockIdx.x) * 4096 + i0 + w * 32 + mt * 16 + q * 4;
      *(f32x4v*)&partial[base] = cs;
    }
  }
  __syncthreads();
  u16* Pb = P + ((size_t)b * 4096 + j0) * 4096 + i0;
#pragma unroll
  for (int p = 0; p < 4; p++) {
    int slot = p * 256 + tid;
    int jr = slot >> 4, c16 = slot & 15;
    *(u16x8v*)&Pb[(size_t)jr * 4096 + c16 * 8] =
        *(const u16x8v*)&sPT[jr * 132 + c16 * 8];
  }
}

// ---------------- kernel 3a: combine partials -> rowsum ----------------
__global__ void k_rsum(const float* __restrict__ partial, float* __restrict__ rowsum) {
  int b = blockIdx.y;
  int i = blockIdx.x * 256 + threadIdx.x;
  const float* p = partial + (size_t)b * 64 * 4096 + i;
  float s = 0.f;
#pragma unroll 8
  for (int jb = 0; jb < 64; jb++) s += p[(size_t)jb * 4096];
  rowsum[(size_t)b * 4096 + i] = s;
}

// ---------------- kernel 3b: vv(bf16) = vv(f16) / rowsum, in place ----------------
__global__ void k_scalev(u16* __restrict__ vvb, const float* __restrict__ rowsum) {
  size_t idx = ((size_t)blockIdx.x * 256 + threadIdx.x) * 8;
  int i = (int)(idx & 4095);
  int b = (int)(idx >> 20);
  f16x8v v = *(f16x8v*)&vvb[idx];   // same bits, read as f16
  const float* rs = rowsum + ((size_t)b << 12) + i;
  u16x8v o;
#pragma unroll
  for (int t = 0; t < 8; t++) o[t] = f2bf((float)v[t] * (1.0f / rs[t]));
  *(u16x8v*)&vvb[idx] = o;
}

// ---------------- kernel 4: AV GEMM (bf16) + residual ----------------
// out[b][c][j] = gamma * sum_i vv'[b][c][i] * P_T[b][j][i] + x[b][c][j]
__global__ void __launch_bounds__(256, 2)
k_av(const u16* __restrict__ vv, const u16* __restrict__ P,
     const float* __restrict__ x, const float* __restrict__ gamma,
     float* __restrict__ out) {
  __shared__ char smem[24576];   // sA [128][64] 16K + sB [64][64] 8K, XOR-swizzled
  u16* sA = (u16*)smem;
  u16* sB = (u16*)(smem + 16384);
  int b = blockIdx.z, c0 = blockIdx.y * 128, j0 = blockIdx.x * 64;
  int tid = threadIdx.x, l = tid & 63, w = tid >> 6;
  int col = l & 15, q = l >> 4;
  const u16* Ab = vv + ((size_t)b * 256 + c0) * 4096;
  const u16* Bb = P + ((size_t)b * 4096 + j0) * 4096;
  f32x4v acc[2][4] = {};
  for (int k0 = 0; k0 < 4096; k0 += 64) {
    __syncthreads();
#pragma unroll
    for (int p = 0; p < 4; p++) {
      int ci = w * 4 + p;
      int r = ci * 8 + (l >> 3);
      int cb = (l & 7) ^ (r & 7);
      gl_lds16(Ab + (size_t)r * 4096 + k0 + cb * 8, smem + ci * 1024);
    }
#pragma unroll
    for (int p = 0; p < 2; p++) {
      int ci = w * 2 + p;
      int r = ci * 8 + (l >> 3);
      int cb = (l & 7) ^ (r & 7);
      gl_lds16(Bb + (size_t)r * 4096 + k0 + cb * 8, smem + 16384 + ci * 1024);
    }
    __syncthreads();
#pragma unroll
    for (int ks = 0; ks < 2; ks++) {
      int phys = (ks * 4 + q) ^ (col & 7);
      s16x8v a[2], bb[4];
#pragma unroll
      for (int mt = 0; mt < 2; mt++)
        a[mt] = *(const s16x8v*)&sA[(w * 32 + mt * 16 + col) * 64 + phys * 8];
#pragma unroll
      for (int nt = 0; nt < 4; nt++)
        bb[nt] = *(const s16x8v*)&sB[(nt * 16 + col) * 64 + phys * 8];
#pragma unroll
      for (int mt = 0; mt < 2; mt++)
#pragma unroll
        for (int nt = 0; nt < 4; nt++)
          acc[mt][nt] = mfma_bf(a[mt], bb[nt], acc[mt][nt]);
    }
  }
  float g = gamma[0];
#pragma unroll
  for (int mt = 0; mt < 2; mt++)
#pragma unroll
    for (int nt = 0; nt < 4; nt++) {
      int c = c0 + w * 32 + mt * 16 + q * 4;
      int j = j0 + nt * 16 + col;
#pragma unroll
      for (int rg = 0; rg < 4; rg++) {
        size_t off = ((size_t)b * 256 + c + rg) * 4096 + j;
        out[off] = g * acc[mt][nt][rg] + x[off];
      }
    }
}

extern "C" void kernel_launch(void* const* d_in, const int* in_sizes, int n_in,
                              void* d_out, int out_size, void* d_ws, size_t ws_size,
                              hipStream_t stream) {
  (void)in_sizes; (void)n_in; (void)out_size; (void)ws_size;
  const float* x  = (const float*)d_in[0];
  const float* wq = (const float*)d_in[1];
  const float* bq = (const float*)d_in[2];
  const float* wk = (const float*)d_in[3];
  const float* bk = (const float*)d_in[4];
  const float* wv = (const float*)d_in[5];
  const float* bv = (const float*)d_in[6];
  const float* gm = (const float*)d_in[7];
  float* out = (float*)d_out;

  char* ws = (char*)d_ws;
  // P (128 MB) overlaps xh/xl lifetime (dead after k_proj). Peak 148.6 MB.
  const size_t P_BYTES = (size_t)4 * 4096 * 4096 * 2;
  u16*  Pt = (u16*)(ws);
  f16*  xh = (f16*)(ws);                          // dies before Pt written
  f16*  xl = (f16*)(ws + (size_t)8 * 1024 * 1024);
  char* tail = ws + P_BYTES;
  f16*  qk = (f16*)(tail);                        // 8 MB: [b][i][0:128]=q,[128:256]=k
  u16*  vv = (u16*)(tail + 8388608);              // 8 MB: f16 then bf16 in place
  f16*  wh = (f16*)(tail + 16777216);
  f16*  wl = (f16*)(tail + 17039360);
  float* bcat    = (float*)(tail + 17301504);
  float* rowsum  = (float*)(tail + 17305600);
  float* partial = (float*)(tail + 17371136);     // 4 MB: [b][64][4096]
  // end: 128 MB + 21565440 B ~= 148.6 MB  (< 161 MB proven available in R2)

  hipLaunchKernelGGL(k_wsplit, dim3(512), dim3(256), 0, stream, wq, bq, wk, bk, wv, bv, wh, wl, bcat);
  hipLaunchKernelGGL(k_xsplit, dim3(64, 4, 4), dim3(256), 0, stream, x, xh, xl);
  hipLaunchKernelGGL(k_proj, dim3(8, 64, 4), dim3(256), 0, stream, xh, xl, wh, wl, bcat, qk, (f16*)vv);
  hipLaunchKernelGGL(k_pmake, dim3(64, 32, 4), dim3(256), 0, stream, qk, Pt, partial);
  hipLaunchKernelGGL(k_rsum, dim3(16, 4), dim3(256), 0, stream, partial, rowsum);
  hipLaunchKernelGGL(k_scalev, dim3(2048), dim3(256), 0, stream, vv, rowsum);
  hipLaunchKernelGGL(k_av, dim3(64, 2, 4), dim3(256), 0, stream, vv, Pt, x, gm, out);
}

// Round 4
// 202.943 us; speedup vs baseline: 2.2105x; 1.1007x over previous
//
#include <hip/hip_runtime.h>
#include <hip/hip_bf16.h>

// ConvSelfAttentionModule: B=4, C=256, CQK=128, N=4096 (64x64), fp32 in/out.
// Pipeline (R4):
//   k_wcvt   : W -> f16 (no hi/lo split: qk f16 storage rounding dominates error)
//   k_xsplit : transpose x[b][c][n] -> xT[b][n][c] f16
//   k_proj   : f16 MFMA GEMM, K=256 single-shot glds staging -> qk, vv
//   k_pmake  : S tiles (K=128 single-shot glds), P=exp(S) raw bf16 -> P_T[b][j][i],
//              partial column sums
//   k_rsum   : rowsum = sum partials
//   k_scalev : vv bf16 <- f16 vv / rowsum
//   k_av     : bf16 NT GEMM, 128x128 tiles, 512 thr, double-buffered glds
//              (1 barrier/iter, transfer of k+1 overlaps MFMA of k), + residual

typedef _Float16 f16;
typedef _Float16 f16x4v __attribute__((ext_vector_type(4)));
typedef _Float16 f16x8v __attribute__((ext_vector_type(8)));
typedef float f32x4v __attribute__((ext_vector_type(4)));
typedef unsigned short u16;
typedef unsigned short u16x4v __attribute__((ext_vector_type(4)));
typedef unsigned short u16x8v __attribute__((ext_vector_type(8)));
typedef short s16x8v __attribute__((ext_vector_type(8)));

static __device__ __forceinline__ f32x4v mfma16(f16x8v a, f16x8v b, f32x4v c) {
  // D[m][n]: a-frag m=lane&15,k=quad*8+j; b-frag (B^T rows) n=lane&15,k=quad*8+j;
  // D: col(n)=lane&15, row(m)=quad*4+reg
  return __builtin_amdgcn_mfma_f32_16x16x32_f16(a, b, c, 0, 0, 0);
}
static __device__ __forceinline__ f32x4v mfma_bf(s16x8v a, s16x8v b, f32x4v c) {
  return __builtin_amdgcn_mfma_f32_16x16x32_bf16(a, b, c, 0, 0, 0);
}
static __device__ __forceinline__ u16 f2bf(float f) {
  union { __hip_bfloat16 h; u16 u; } cv;
  cv.h = __float2bfloat16(f);  // RNE
  return cv.u;
}

#define AS1q __attribute__((address_space(1)))
#define AS3q __attribute__((address_space(3)))
static __device__ __forceinline__ void gl_lds16(const void* g, void* l) {
  // 16B per lane; LDS dest = wave-uniform base + lane*16 (per-lane global src OK)
  __builtin_amdgcn_global_load_lds((const AS1q unsigned int*)g,
                                   (AS3q unsigned int*)l, 16, 0, 0);
}

// ---------------- kernel 0a: weight convert ----------------
__global__ void k_wcvt(const float* __restrict__ wq, const float* __restrict__ bq,
                       const float* __restrict__ wk, const float* __restrict__ bk,
                       const float* __restrict__ wv, const float* __restrict__ bv,
                       f16* __restrict__ wh, float* __restrict__ bcat) {
  int o = blockIdx.x;          // 512 rows: 0-127 q, 128-255 k, 256-511 v
  int c = threadIdx.x;         // 256
  const float* wrow; float bias;
  if (o < 128)      { wrow = wq + (size_t)o * 256;         bias = bq[o]; }
  else if (o < 256) { wrow = wk + (size_t)(o - 128) * 256; bias = bk[o - 128]; }
  else              { wrow = wv + (size_t)(o - 256) * 256; bias = bv[o - 256]; }
  wh[(size_t)o * 256 + c] = (f16)wrow[c];
  if (c == 0) bcat[o] = bias;
}

// ---------------- kernel 0b: x transpose ----------------
// x[b][c][n] f32 -> xT[b][n][c] f16
__global__ void k_xsplit(const float* __restrict__ x, f16* __restrict__ xh) {
  __shared__ float t[64][65];
  int b = blockIdx.z, c0 = blockIdx.y * 64, n0 = blockIdx.x * 64;
  int tx = threadIdx.x & 63, ty = threadIdx.x >> 6;
  const float* xb = x + ((size_t)b * 256 + c0) * 4096 + n0;
#pragma unroll
  for (int r = ty; r < 64; r += 4) t[r][tx] = xb[(size_t)r * 4096 + tx];
  __syncthreads();
  f16* dh = xh + ((size_t)b * 4096 + n0) * 256 + c0;
#pragma unroll
  for (int r = ty; r < 64; r += 4)
    dh[(size_t)r * 256 + tx] = (f16)t[tx][r];
}

// ---------------- kernel 1: projections (f16 NT GEMM, K=256 single-shot) ----------------
// D[i][o] = sum_c xT[i][c]*W[o][c] + b[o];  o<256 -> qk[b][i][o] ; else vv[b][o-256][i]
// LDS: sA [64 rows][256 f16] 32KB + sW 32KB, XOR-swizzled 16B groups, glds staged.
__global__ void __launch_bounds__(256, 2)
k_proj(const f16* __restrict__ xh, const f16* __restrict__ wh,
       const float* __restrict__ bcat, f16* __restrict__ qk, f16* __restrict__ vv) {
  extern __shared__ char smem[];   // 64KB
  int b = blockIdx.z, m0 = blockIdx.y * 64, n0 = blockIdx.x * 64;
  int tid = threadIdx.x, l = tid & 63, w = tid >> 6;
  int col = l & 15, quad = l >> 4;
  const f16* Ag = xh + ((size_t)b * 4096 + m0) * 256;
  const f16* Wg = wh + (size_t)n0 * 256;
  int rloc = l >> 5;   // row within 1KB chunk (2 rows of 512B)
  int l5 = l & 31;     // 16B group within row
  // stage: 32 chunks A + 32 chunks W; LDS[r][p] = G[r][p ^ (r&31)]
#pragma unroll
  for (int p = 0; p < 8; p++) {
    int ci = w * 8 + p;
    int r = ci * 2 + rloc;
    int g = l5 ^ (r & 31);
    gl_lds16(Ag + (size_t)r * 256 + g * 8, smem + ci * 1024);
    gl_lds16(Wg + (size_t)r * 256 + g * 8, smem + 32768 + ci * 1024);
  }
  __syncthreads();
  const char* sA = smem;
  const char* sW = smem + 32768;
  f32x4v acc[4] = {};
  int ar = w * 16 + col;
#pragma unroll
  for (int ks = 0; ks < 8; ks++) {
    int G = ks * 4 + quad;
    f16x8v a = *(const f16x8v*)(sA + ar * 512 + ((G ^ (ar & 31)) * 16));
#pragma unroll
    for (int nt = 0; nt < 4; nt++) {
      int wr = nt * 16 + col;
      f16x8v bb = *(const f16x8v*)(sW + wr * 512 + ((G ^ (wr & 31)) * 16));
      acc[nt] = mfma16(a, bb, acc[nt]);
    }
  }
  bool isqk = (n0 < 256);  // block-uniform
#pragma unroll
  for (int nt = 0; nt < 4; nt++) {
    int o = n0 + nt * 16 + col;
    float bias = bcat[o];
    if (isqk) {
#pragma unroll
      for (int rg = 0; rg < 4; rg++) {
        int i = m0 + w * 16 + quad * 4 + rg;
        qk[((size_t)b * 4096 + i) * 256 + o] = (f16)(acc[nt][rg] + bias);
      }
    } else {
      int i = m0 + w * 16 + quad * 4;
      f16x4v pv;
#pragma unroll
      for (int rg = 0; rg < 4; rg++) pv[rg] = (f16)(acc[nt][rg] + bias);
      *(f16x4v*)&vv[((size_t)b * 256 + (o - 256)) * 4096 + i] = pv;
    }
  }
}

// ---------------- kernel 2: P^T materialize + partial column sums ----------------
// Per block: S for (128 i) x (64 j), K=128 single-shot via glds.
// P = exp(S) raw (bf16, range-safe) -> LDS transpose -> P_T[b][j][i] coalesced.
// partial[b][jblk][i] = sum over this tile's 64 j of exp(s_ij).
__global__ void __launch_bounds__(256, 2)
k_pmake(const f16* __restrict__ qk, u16* __restrict__ P, float* __restrict__ partial) {
  __shared__ char smem[49152];   // sQ [128][128] (32K) + sK [64][128] (16K)
  f16* sQ = (f16*)smem;
  f16* sK = (f16*)(smem + 32768);
  u16* sPT = (u16*)smem;         // [64][132] overlay after compute
  int b = blockIdx.z, i0 = blockIdx.y * 128, j0 = blockIdx.x * 64;
  int tid = threadIdx.x, l = tid & 63, w = tid >> 6;
  int col = l & 15, q = l >> 4;
  const f16* qb = qk + (size_t)b * 4096 * 256;
#pragma unroll
  for (int p = 0; p < 8; p++) {
    int ci = w * 8 + p;
    int r = ci * 4 + (l >> 4);
    int cb = (l & 15) ^ (r & 15);
    gl_lds16(qb + (size_t)(i0 + r) * 256 + cb * 8, smem + ci * 1024);
  }
#pragma unroll
  for (int p = 0; p < 4; p++) {
    int ci = w * 4 + p;
    int r = ci * 4 + (l >> 4);
    int cb = (l & 15) ^ (r & 15);
    gl_lds16(qb + (size_t)(j0 + r) * 256 + 128 + cb * 8, smem + 32768 + ci * 1024);
  }
  __syncthreads();
  f32x4v acc[2][4] = {};
#pragma unroll
  for (int ks = 0; ks < 4; ks++) {
    int phys = (ks * 4 + q) ^ col;
    f16x8v a[2], bb[4];
#pragma unroll
    for (int mt = 0; mt < 2; mt++)
      a[mt] = *(const f16x8v*)&sQ[(w * 32 + mt * 16 + col) * 128 + phys * 8];
#pragma unroll
    for (int nt = 0; nt < 4; nt++)
      bb[nt] = *(const f16x8v*)&sK[(nt * 16 + col) * 128 + phys * 8];
#pragma unroll
    for (int mt = 0; mt < 2; mt++)
#pragma unroll
      for (int nt = 0; nt < 4; nt++)
        acc[mt][nt] = mfma16(a[mt], bb[nt], acc[mt][nt]);
  }
  float pe[2][4][4];
#pragma unroll
  for (int mt = 0; mt < 2; mt++)
#pragma unroll
    for (int nt = 0; nt < 4; nt++)
#pragma unroll
      for (int rg = 0; rg < 4; rg++)
        pe[mt][nt][rg] = __expf(acc[mt][nt][rg]);
  __syncthreads();  // done with sQ/sK -> reuse as sPT
#pragma unroll
  for (int mt = 0; mt < 2; mt++) {
    int ib = w * 32 + mt * 16 + q * 4;
#pragma unroll
    for (int nt = 0; nt < 4; nt++) {
      u16x4v pw;
#pragma unroll
      for (int rg = 0; rg < 4; rg++) pw[rg] = f2bf(pe[mt][nt][rg]);
      *(u16x4v*)&sPT[(nt * 16 + col) * 132 + ib] = pw;
    }
  }
#pragma unroll
  for (int mt = 0; mt < 2; mt++) {
    f32x4v cs;
#pragma unroll
    for (int rg = 0; rg < 4; rg++) {
      float t = pe[mt][0][rg] + pe[mt][1][rg] + pe[mt][2][rg] + pe[mt][3][rg];
#pragma unroll
      for (int d = 1; d < 16; d <<= 1) t += __shfl_xor(t, d, 64);
      cs[rg] = t;
    }
    if (col == 0) {
      size_t base = ((size_t)b * 64 + blockIdx.x) * 4096 + i0 + w * 32 + mt * 16 + q * 4;
      *(f32x4v*)&partial[base] = cs;
    }
  }
  __syncthreads();
  u16* Pb = P + ((size_t)b * 4096 + j0) * 4096 + i0;
#pragma unroll
  for (int p = 0; p < 4; p++) {
    int slot = p * 256 + tid;
    int jr = slot >> 4, c16 = slot & 15;
    *(u16x8v*)&Pb[(size_t)jr * 4096 + c16 * 8] =
        *(const u16x8v*)&sPT[jr * 132 + c16 * 8];
  }
}

// ---------------- kernel 3a: combine partials -> rowsum ----------------
__global__ void k_rsum(const float* __restrict__ partial, float* __restrict__ rowsum) {
  int b = blockIdx.y;
  int i = blockIdx.x * 256 + threadIdx.x;
  const float* p = partial + (size_t)b * 64 * 4096 + i;
  float s = 0.f;
#pragma unroll 8
  for (int jb = 0; jb < 64; jb++) s += p[(size_t)jb * 4096];
  rowsum[(size_t)b * 4096 + i] = s;
}

// ---------------- kernel 3b: vv(bf16) = vv(f16) / rowsum, in place ----------------
__global__ void k_scalev(u16* __restrict__ vvb, const float* __restrict__ rowsum) {
  size_t idx = ((size_t)blockIdx.x * 256 + threadIdx.x) * 8;
  int i = (int)(idx & 4095);
  int b = (int)(idx >> 20);
  f16x8v v = *(f16x8v*)&vvb[idx];
  const float* rs = rowsum + ((size_t)b << 12) + i;
  u16x8v o;
#pragma unroll
  for (int t = 0; t < 8; t++) o[t] = f2bf((float)v[t] * (1.0f / rs[t]));
  *(u16x8v*)&vvb[idx] = o;
}

// ---------------- kernel 4: AV GEMM (bf16), 128x128 tile, dbuf pipeline ----------------
// out[b][c][j] = gamma * sum_i vv'[b][c][i] * P_T[b][j][i] + x[b][c][j]
// 512 threads (8 waves: cw=w>>2 over 2x64 c, jw=w&3 over 4x32 j). BK=64.
// LDS 2 x (A 16KB | B 16KB); one __syncthreads per iter; glds of tile k+1
// issued after the barrier overlaps MFMA of tile k.
__global__ void __launch_bounds__(512, 2)
k_av(const u16* __restrict__ vv, const u16* __restrict__ P,
     const float* __restrict__ x, const float* __restrict__ gamma,
     float* __restrict__ out) {
  extern __shared__ char smem[];  // 64KB
  int b = blockIdx.z, c0 = blockIdx.x * 128, j0 = blockIdx.y * 128;
  int tid = threadIdx.x, l = tid & 63, w = tid >> 6;
  int col = l & 15, q = l >> 4;
  int cw = w >> 2, jw = w & 3;
  const u16* Ab = vv + ((size_t)b * 256 + c0) * 4096;
  const u16* Bb = P + ((size_t)b * 4096 + j0) * 4096;
  int rloc = l >> 3;   // row within 1KB chunk (8 rows of 128B)
  int gsw = l & 7;     // 16B group within row
  f32x4v acc[4][2] = {};
  // prologue: stage tile 0 into buf 0
#pragma unroll
  for (int p = 0; p < 4; p++) {
    int ci = w * 4 + p;                       // 0..15 A rows, 16..31 B rows
    int rr = (ci & 15) * 8 + rloc;
    int g = gsw ^ (rr & 7);
    const u16* src = (ci < 16 ? Ab : Bb) + (size_t)rr * 4096 + g * 8;
    gl_lds16(src, smem + ci * 1024);
  }
  for (int it = 0; it < 64; it++) {
    __syncthreads();   // drains glds of current buf (vmcnt) + prev reads
    if (it < 63) {
      int k0 = (it + 1) * 64;
      char* nb = smem + ((it + 1) & 1) * 32768;
#pragma unroll
      for (int p = 0; p < 4; p++) {
        int ci = w * 4 + p;
        int rr = (ci & 15) * 8 + rloc;
        int g = gsw ^ (rr & 7);
        const u16* src = (ci < 16 ? Ab : Bb) + (size_t)rr * 4096 + k0 + g * 8;
        gl_lds16(src, nb + ci * 1024);
      }
    }
    const char* cur = smem + (it & 1) * 32768;
#pragma unroll
    for (int ks = 0; ks < 2; ks++) {
      int G = ks * 4 + q;
      s16x8v a[4], bb[2];
#pragma unroll
      for (int mt = 0; mt < 4; mt++) {
        int ar = cw * 64 + mt * 16 + col;
        a[mt] = *(const s16x8v*)(cur + ar * 128 + ((G ^ (ar & 7)) * 16));
      }
#pragma unroll
      for (int nt = 0; nt < 2; nt++) {
        int jr = jw * 32 + nt * 16 + col;
        bb[nt] = *(const s16x8v*)(cur + 16384 + jr * 128 + ((G ^ (jr & 7)) * 16));
      }
#pragma unroll
      for (int mt = 0; mt < 4; mt++)
#pragma unroll
        for (int nt = 0; nt < 2; nt++)
          acc[mt][nt] = mfma_bf(a[mt], bb[nt], acc[mt][nt]);
    }
  }
  float g = gamma[0];
#pragma unroll
  for (int mt = 0; mt < 4; mt++)
#pragma unroll
    for (int nt = 0; nt < 2; nt++) {
      int c = c0 + cw * 64 + mt * 16 + q * 4;
      int j = j0 + jw * 32 + nt * 16 + col;
#pragma unroll
      for (int rg = 0; rg < 4; rg++) {
        size_t off = ((size_t)b * 256 + c + rg) * 4096 + j;
        out[off] = g * acc[mt][nt][rg] + x[off];
      }
    }
}

extern "C" void kernel_launch(void* const* d_in, const int* in_sizes, int n_in,
                              void* d_out, int out_size, void* d_ws, size_t ws_size,
                              hipStream_t stream) {
  (void)in_sizes; (void)n_in; (void)out_size; (void)ws_size;
  const float* x  = (const float*)d_in[0];
  const float* wq = (const float*)d_in[1];
  const float* bq = (const float*)d_in[2];
  const float* wk = (const float*)d_in[3];
  const float* bk = (const float*)d_in[4];
  const float* wv = (const float*)d_in[5];
  const float* bv = (const float*)d_in[6];
  const float* gm = (const float*)d_in[7];
  float* out = (float*)d_out;

  char* ws = (char*)d_ws;
  // P (128 MB) overlaps xh lifetime (xh dead after k_proj). Peak ~148.3 MB.
  const size_t P_BYTES = (size_t)4 * 4096 * 4096 * 2;
  u16*  Pt = (u16*)(ws);
  f16*  xh = (f16*)(ws);                     // 8 MB, dies before Pt written
  char* tail = ws + P_BYTES;
  f16*  qk = (f16*)(tail);                   // 8 MB: [b][i][0:128]=q,[128:256]=k
  u16*  vv = (u16*)(tail + 8388608);         // 8 MB: f16 then bf16 in place
  f16*  wh = (f16*)(tail + 16777216);        // 256 KB
  float* bcat    = (float*)(tail + 17039360);
  float* rowsum  = (float*)(tail + 17041408);
  float* partial = (float*)(tail + 17106944); // 4 MB: [b][64][4096]

  hipLaunchKernelGGL(k_wcvt, dim3(512), dim3(256), 0, stream, wq, bq, wk, bk, wv, bv, wh, bcat);
  hipLaunchKernelGGL(k_xsplit, dim3(64, 4, 4), dim3(256), 0, stream, x, xh);
  hipLaunchKernelGGL(k_proj, dim3(8, 64, 4), dim3(256), 65536, stream, xh, wh, bcat, qk, (f16*)vv);
  hipLaunchKernelGGL(k_pmake, dim3(64, 32, 4), dim3(256), 0, stream, qk, Pt, partial);
  hipLaunchKernelGGL(k_rsum, dim3(16, 4), dim3(256), 0, stream, partial, rowsum);
  hipLaunchKernelGGL(k_scalev, dim3(2048), dim3(256), 0, stream, vv, rowsum);
  hipLaunchKernelGGL(k_av, dim3(2, 32, 4), dim3(512), 65536, stream, vv, Pt, x, gm, out);
}